// Round 15
// baseline (2107.143 us; speedup 1.0000x reference)
//
#include <hip/hip_runtime.h>
#include <hip/hip_bf16.h>
#include <stdint.h>

// E60bGatedResidualCell — R15: R14 + wave-role separation (clean vmcnt queues).
// out[t] = h²σ(h); h_{t+1} = h_t + g_t ⊙ tanh(h_t W_hᵀ + x_t W_xᵀ + b)
// fp32 outputs. P in out_h[t+1] (read pre-overwrite), G in out_o[t] (same).
// 256 WGs = 8 chain-groups (4 b) × 32 e-slices. Wh in VGPRs (128 f32/thr).
// In-order vmem return => vmcnt(0) waits for EVERYTHING older in the wave's
// queue. Fix: w2 polls flags (clean queue); P/G prefetched one step early on
// w0/w1; PO/PH output stores on w3 via LDS hn hand-off (drain during poll).
// h_ex/flags at agent scope (sc1; R11: no suffix = CU scope = stale/deadlock).

#define T_DIM 512
#define B_DIM 32
#define D_DIM 1024
#define M_DIM (T_DIM*B_DIM)

typedef __attribute__((ext_vector_type(4))) float f32x4;
typedef __attribute__((ext_vector_type(2))) float f32x2;
typedef __attribute__((ext_vector_type(8))) short bf16x8;

__device__ inline unsigned short f2b(float f){
  union { float f; uint32_t u; } c; c.f = f;
  uint32_t u = c.u + 0x7fffu + ((c.u >> 16) & 1u);   // RNE
  return (unsigned short)(u >> 16);
}
__device__ inline float b2f(unsigned short h){
  union { uint32_t u; float f; } c; c.u = ((uint32_t)h) << 16;
  return c.f;
}

// ---- init: zero out_h[0], h_ex buf0 of each group, flags ----------------------
__global__ void init_kernel(float* __restrict__ out_h0,
                            float* __restrict__ h_ex,
                            uint32_t* __restrict__ flags){
  int i = blockIdx.x*blockDim.x + threadIdx.x;   // 0..32767
  out_h0[i] = 0.f;
  int g = i >> 12, j = i & 4095;
  h_ex[(size_t)g*8192 + j] = 0.f;                // buf0 of each of 8 groups
  if (i < 4096) flags[i] = 0;
}

// ---- proj (split-bf16 MFMA, fp32 out): OUT[m,n] = f(sum_k X[m,k]*W[n,k]+bias) -
template<int MODE>
__global__ __launch_bounds__(256, 2)
void proj_m(const float* __restrict__ X, const float* __restrict__ W,
            const float* __restrict__ bias, float* __restrict__ OUT)
{
  __shared__ unsigned short Ah[128*64];
  __shared__ unsigned short Al[128*64];
  __shared__ unsigned short Bh[128*64];
  __shared__ unsigned short Bl[128*64];
  char* AhB=(char*)Ah; char* AlB=(char*)Al; char* BhB=(char*)Bh; char* BlB=(char*)Bl;
  const int tid  = threadIdx.x;
  const int lane = tid & 63;
  const int wave = tid >> 6;
  const int m0 = blockIdx.y * 128;
  const int n0 = blockIdx.x * 128;
  const int wm = (wave >> 1) * 64;
  const int wn = (wave & 1) * 64;
  const int fr = lane & 15;
  const int fq = lane >> 4;

  f32x4 acc[4][4];
  #pragma unroll
  for (int i=0;i<4;++i)
    #pragma unroll
    for (int j=0;j<4;++j) acc[i][j] = (f32x4){0.f,0.f,0.f,0.f};

  for (int kt = 0; kt < D_DIM/64; ++kt) {
    #pragma unroll
    for (int c = 0; c < 4; ++c) {
      int idx = tid + c*256;
      int row = idx >> 3;
      int k8  = idx & 7;
      const float* ga = X + (size_t)(m0+row)*D_DIM + kt*64 + k8*8;
      const float* gb = W + (size_t)(n0+row)*D_DIM + kt*64 + k8*8;
      f32x4 a0 = *(const f32x4*)ga, a1 = *(const f32x4*)(ga+4);
      f32x4 b0 = *(const f32x4*)gb, b1 = *(const f32x4*)(gb+4);
      bf16x8 vah, val, vbh, vbl;
      #pragma unroll
      for (int j=0;j<4;++j){
        unsigned short h;
        h = f2b(a0[j]); vah[j]   = (short)h; val[j]   = (short)f2b(a0[j]-b2f(h));
        h = f2b(a1[j]); vah[4+j] = (short)h; val[4+j] = (short)f2b(a1[j]-b2f(h));
        h = f2b(b0[j]); vbh[j]   = (short)h; vbl[j]   = (short)f2b(b0[j]-b2f(h));
        h = f2b(b1[j]); vbh[4+j] = (short)h; vbl[4+j] = (short)f2b(b1[j]-b2f(h));
      }
      int lb = row*128 + ((k8*16) ^ ((row&7)<<4));
      *(bf16x8*)(AhB + lb) = vah;
      *(bf16x8*)(AlB + lb) = val;
      *(bf16x8*)(BhB + lb) = vbh;
      *(bf16x8*)(BlB + lb) = vbl;
    }
    __syncthreads();
    #pragma unroll
    for (int kk=0; kk<2; ++kk) {
      bf16x8 afh[4], afl[4], bfh[4], bfl[4];
      #pragma unroll
      for (int i=0;i<4;++i){
        int row = wm+i*16+fr;
        int off = row*128 + ((kk*64 + fq*16) ^ ((row&7)<<4));
        afh[i] = *(const bf16x8*)(AhB + off);
        afl[i] = *(const bf16x8*)(AlB + off);
      }
      #pragma unroll
      for (int j=0;j<4;++j){
        int row = wn+j*16+fr;
        int off = row*128 + ((kk*64 + fq*16) ^ ((row&7)<<4));
        bfh[j] = *(const bf16x8*)(BhB + off);
        bfl[j] = *(const bf16x8*)(BlB + off);
      }
      #pragma unroll
      for (int i=0;i<4;++i)
        #pragma unroll
        for (int j=0;j<4;++j){
          acc[i][j] = __builtin_amdgcn_mfma_f32_16x16x32_bf16(afh[i], bfh[j], acc[i][j], 0,0,0);
          acc[i][j] = __builtin_amdgcn_mfma_f32_16x16x32_bf16(afh[i], bfl[j], acc[i][j], 0,0,0);
          acc[i][j] = __builtin_amdgcn_mfma_f32_16x16x32_bf16(afl[i], bfh[j], acc[i][j], 0,0,0);
        }
    }
    __syncthreads();
  }
  #pragma unroll
  for (int j=0;j<4;++j) {
    int col = n0 + wn + j*16 + fr;
    float bv = bias[col];
    #pragma unroll
    for (int i=0;i<4;++i) {
      int rowb = m0 + wm + i*16 + fq*4;
      #pragma unroll
      for (int r=0;r<4;++r) {
        float v = acc[i][j][r] + bv;
        if (MODE==1) v = 1.f/(1.f + expf(-v));
        OUT[(size_t)(rowb+r)*D_DIM + col] = v;
      }
    }
  }
}

// ---- persistent recurrence ----------------------------------------------------
__global__ __launch_bounds__(256, 1)
void rnn_persist(const float* __restrict__ Wh,
                 float* PO,                 // out_o: G (read) / out (write)
                 float* PH,                 // out_h: P (read@t+1 slot) / h (write)
                 float* __restrict__ h_ex,  // [8 grp][2 buf][4096 f32]
                 uint32_t* __restrict__ flags)  // [8][32] stride 16 u32
{
  __shared__ char  hsb[4*4096];          // h staged, XOR-swizzled 16B granules (16KB)
  __shared__ float part[16*137];         // k-partials, padded stride (8.8KB)
  __shared__ float hout[128];            // epilogue hn hand-off to w3 (512B)

  const int tid = threadIdx.x;
  const int blk = blockIdx.x;
  const int g   = blk & 7;               // chain-group 0..7 (XCD-interleaved)
  const int sl  = blk >> 3;              // e-slice 0..31
  const int e0  = sl * 32;
  const int b0  = g * 4;
  const int e2  = tid & 15;              // e-pair 0..15
  const int kc  = tid >> 4;              // k-chunk 0..15 (64 k each)

  // ---- one-time: Wh slice into registers (2 e-cols x 64 k per thread) ----
  f32x4 wh0[16], wh1[16];
  {
    const f32x4* wp0 = (const f32x4*)(Wh + (size_t)(e0 + 2*e2 + 0)*D_DIM + kc*64);
    const f32x4* wp1 = (const f32x4*)(Wh + (size_t)(e0 + 2*e2 + 1)*D_DIM + kc*64);
    #pragma unroll
    for (int i = 0; i < 16; ++i) { wh0[i] = wp0[i]; wh1[i] = wp1[i]; }
  }

  const int bl = tid >> 5;               // epilogue roles (tid<128): b 0..3
  const int el = tid & 31;               // e 0..31
  float hold = 0.f;                      // this thread's own h[b0+bl][e0+el]

  // prefetch P/G for t=0 (w0/w1 only; arrives during first stage)
  float Pv = 0.f, Gv = 0.f;
  if (tid < 128) {
    size_t idx0 = (size_t)(b0 + bl)*D_DIM + e0 + el;
    Pv = PH[idx0 + 32768];
    Gv = PO[idx0];
  }

  for (int t = 0; t < T_DIM; ++t) {
    size_t idx_out = (size_t)t*32768 + (size_t)(b0 + bl)*D_DIM + e0 + el;

    // poll on w2 (tid 128..159): their vmem queue is clean -> vmcnt(0) is cheap
    if (t > 0 && tid >= 128 && tid < 160) {
      const uint32_t* fp = flags + (size_t)(g*32 + (tid - 128))*16;
      uint32_t v;
      while (true) {
        asm volatile("global_load_dword %0, %1, off sc1" : "=v"(v) : "v"(fp) : "memory");
        asm volatile("s_waitcnt vmcnt(0)" ::: "memory");
        if (v >= (uint32_t)t) break;
        __builtin_amdgcn_s_sleep(1);
      }
    }
    __syncthreads();

    // stage h[4][1024] from h_ex[g][t&1] — pipelined agent-scope 16B loads
    {
      const char* hsrc = (const char*)(h_ex + (size_t)(g*2 + (t&1))*4096) + tid*16;
      f32x4 r0, r1, r2, r3;
      asm volatile("global_load_dwordx4 %0, %1, off sc1" : "=v"(r0) : "v"(hsrc)         : "memory");
      asm volatile("global_load_dwordx4 %0, %1, off sc1" : "=v"(r1) : "v"(hsrc + 4096)  : "memory");
      asm volatile("global_load_dwordx4 %0, %1, off sc1" : "=v"(r2) : "v"(hsrc + 8192)  : "memory");
      asm volatile("global_load_dwordx4 %0, %1, off sc1" : "=v"(r3) : "v"(hsrc + 12288) : "memory");
      asm volatile("s_waitcnt vmcnt(0)" ::: "memory");
      __builtin_amdgcn_sched_barrier(0);
      // scatter to LDS with XOR swizzle: granule g16 -> g16 ^ (g16>>4), per b-plane
      #pragma unroll
      for (int i = 0; i < 4; ++i) {
        int G   = i*256 + tid;
        int bq  = G >> 8;
        int g16 = G & 255;
        int g16s = g16 ^ (g16 >> 4);
        f32x4 v = (i==0) ? r0 : (i==1) ? r1 : (i==2) ? r2 : r3;
        *(f32x4*)(hsb + bq*4096 + g16s*16) = v;
      }
    }
    __syncthreads();

    // compute: acc[b][u] = sum over this thread's 64-k chunk (conflict-free reads)
    float acc[4][2];
    #pragma unroll
    for (int b = 0; b < 4; ++b) { acc[b][0] = 0.f; acc[b][1] = 0.f; }
    #pragma unroll
    for (int i = 0; i < 16; ++i) {
      f32x4 w0 = wh0[i], w1 = wh1[i];
      #pragma unroll
      for (int b = 0; b < 4; ++b) {
        f32x4 hv = *(const f32x4*)(hsb + b*4096 + kc*256 + ((i ^ kc) << 4));
        float d0 = hv[0]*w0[0] + hv[1]*w0[1] + hv[2]*w0[2] + hv[3]*w0[3];
        float d1 = hv[0]*w1[0] + hv[1]*w1[1] + hv[2]*w1[2] + hv[3]*w1[3];
        acc[b][0] += d0;
        acc[b][1] += d1;
      }
    }
    #pragma unroll
    for (int b = 0; b < 4; ++b) {
      part[kc*137 + b*32 + 2*e2 + 0] = acc[b][0];
      part[kc*137 + b*32 + 2*e2 + 1] = acc[b][1];
    }
    __syncthreads();

    // reduce + epilogue (tid<128): h_ex store + LDS hand-off; NO output stores here
    if (tid < 128) {
      float pre = 0.f;
      #pragma unroll
      for (int q = 0; q < 16; ++q) pre += part[q*137 + bl*32 + el];
      pre += Pv;
      float th = tanhf(pre);
      float hn = hold + Gv*th;
      hold = hn;
      hout[tid] = hn;
      float* hdst = h_ex + (size_t)(g*2 + ((t+1)&1))*4096 + bl*1024 + e0 + el;
      asm volatile("global_store_dword %0, %1, off sc1" :: "v"(hdst), "v"(hn) : "memory");
    }
    asm volatile("s_waitcnt vmcnt(0)" ::: "memory");
    __syncthreads();

    // flag release: h data ACKed at agent coherence point — plain sc1 store.
    if (tid == 0) {
      uint32_t fv = (uint32_t)(t+1);
      uint32_t* fptr = flags + (size_t)(g*32 + sl)*16;
      asm volatile("global_store_dword %0, %1, off sc1" :: "v"(fptr), "v"(fv) : "memory");
    }

    // prefetch P/G for t+1 on w0/w1 — a full step ahead of use
    if (t + 1 < T_DIM && tid < 128) {
      size_t idx_n = (size_t)(t+1)*32768 + (size_t)(b0 + bl)*D_DIM + e0 + el;
      Pv = PH[idx_n + 32768];
      Gv = PO[idx_n];
    }

    // output stores on w3 (tid 192..255): drain during the next poll phase
    if (tid >= 192) {
      int j  = tid - 192;
      int bb = j >> 4;                  // 0..3
      int ep = (j & 15) * 2;            // even e-offset 0..30
      float h0v = hout[bb*32 + ep];
      float h1v = hout[bb*32 + ep + 1];
      f32x2 ov, hv2;
      ov[0] = h0v*h0v*(1.f/(1.f + expf(-h0v)));
      ov[1] = h1v*h1v*(1.f/(1.f + expf(-h1v)));
      hv2[0] = h0v; hv2[1] = h1v;
      size_t ixw = (size_t)t*32768 + (size_t)(b0 + bb)*D_DIM + e0 + ep;
      *(f32x2*)(PO + ixw) = ov;                 // out[t]
      *(f32x2*)(PH + ixw + 32768) = hv2;        // h[t+1] (overwrites P slot)
    }
  }
}

extern "C" void kernel_launch(void* const* d_in, const int* in_sizes, int n_in,
                              void* d_out, int out_size, void* d_ws, size_t ws_size,
                              hipStream_t stream) {
  const float* x  = (const float*)d_in[0];
  const float* Wh = (const float*)d_in[1];
  const float* Wx = (const float*)d_in[2];
  const float* Wg = (const float*)d_in[3];
  const float* b  = (const float*)d_in[4];
  const float* bg = (const float*)d_in[5];

  float* out_o = (float*)d_out;                       // [T,B,D] fp32
  float* out_h = out_o + (size_t)M_DIM*D_DIM;         // [T+1,B,D] fp32

  char* ws = (char*)d_ws;
  float*    h_ex  = (float*)ws;                       // 8*2*16KB = 256 KB
  uint32_t* flags = (uint32_t*)(ws + (256<<10));      // 16 KB

  init_kernel<<<128, 256, 0, stream>>>(out_h, h_ex, flags);
  proj_m<1><<<dim3(8,128), 256, 0, stream>>>(x, Wg, bg, out_o);           // G -> out_o[t]
  proj_m<0><<<dim3(8,128), 256, 0, stream>>>(x, Wx, b,  out_h + 32768);   // P -> out_h[t+1]
  rnn_persist<<<256, 256, 0, stream>>>(Wh, out_o, out_h, h_ex, flags);
}

// Round 17
// 1649.120 us; speedup vs baseline: 1.2777x; 1.2777x over previous
//
#include <hip/hip_runtime.h>
#include <hip/hip_bf16.h>
#include <stdint.h>

// E60bGatedResidualCell — R17: NaN-gated 16-slot h_ex exchange (2-hop sync),
// built only from proven parts (R13 retry shape + rule-18 fix + R14 layout).
// out[t] = h²σ(h); h_{t+1} = h_t + g_t ⊙ tanh(h_t W_hᵀ + x_t W_xᵀ + b)
// fp32 outputs. P in out_h[t+1] (read@t+1-ahead prefetch, pre-overwrite),
// G in out_o[t] (same). h exchange: d_ws h_ex[8 grp][16 slot][4][1024] f32,
// init: slot0=h0=0, slots1..15=0x7FC00000 marker. Producers store h (sc1) to
// slot (t+1)&15 and pre-clear their float in slot (t+9)&15 (consumed >=8 steps
// ago by lockstep induction). Consumers retry-load granules until != marker.
// No flags, no producer vmcnt/barrier. 2 barriers/step (hsb, part).

#define T_DIM 512
#define B_DIM 32
#define D_DIM 1024
#define M_DIM (T_DIM*B_DIM)
#define NANB 0x7FC00000u

typedef __attribute__((ext_vector_type(4))) float f32x4;
typedef __attribute__((ext_vector_type(4))) int   i32x4;
typedef __attribute__((ext_vector_type(8))) short bf16x8;

__device__ inline unsigned short f2b(float f){
  union { float f; uint32_t u; } c; c.f = f;
  uint32_t u = c.u + 0x7fffu + ((c.u >> 16) & 1u);   // RNE
  return (unsigned short)(u >> 16);
}
__device__ inline float b2f(unsigned short h){
  union { uint32_t u; float f; } c; c.u = ((uint32_t)h) << 16;
  return c.f;
}

// ---- init: out_h[0]=0; h_ex slot0=0, slots1..15=NaN marker (all groups) ------
__global__ void init_kernel(float* __restrict__ out_h0, uint32_t* __restrict__ h_ex){
  int i = blockIdx.x*blockDim.x + threadIdx.x;       // 0..524287
  if (i < 32768) out_h0[i] = 0.f;
  int slot = (i >> 12) & 15;                         // [g][slot][4096]
  h_ex[i] = (slot == 0) ? 0u : NANB;
}

// ---- proj (split-bf16 MFMA, fp32 out): OUT[m,n] = f(sum_k X[m,k]*W[n,k]+bias) -
template<int MODE>
__global__ __launch_bounds__(256, 2)
void proj_m(const float* __restrict__ X, const float* __restrict__ W,
            const float* __restrict__ bias, float* __restrict__ OUT)
{
  __shared__ unsigned short Ah[128*64];
  __shared__ unsigned short Al[128*64];
  __shared__ unsigned short Bh[128*64];
  __shared__ unsigned short Bl[128*64];
  char* AhB=(char*)Ah; char* AlB=(char*)Al; char* BhB=(char*)Bh; char* BlB=(char*)Bl;
  const int tid  = threadIdx.x;
  const int lane = tid & 63;
  const int wave = tid >> 6;
  const int m0 = blockIdx.y * 128;
  const int n0 = blockIdx.x * 128;
  const int wm = (wave >> 1) * 64;
  const int wn = (wave & 1) * 64;
  const int fr = lane & 15;
  const int fq = lane >> 4;

  f32x4 acc[4][4];
  #pragma unroll
  for (int i=0;i<4;++i)
    #pragma unroll
    for (int j=0;j<4;++j) acc[i][j] = (f32x4){0.f,0.f,0.f,0.f};

  for (int kt = 0; kt < D_DIM/64; ++kt) {
    #pragma unroll
    for (int c = 0; c < 4; ++c) {
      int idx = tid + c*256;
      int row = idx >> 3;
      int k8  = idx & 7;
      const float* ga = X + (size_t)(m0+row)*D_DIM + kt*64 + k8*8;
      const float* gb = W + (size_t)(n0+row)*D_DIM + kt*64 + k8*8;
      f32x4 a0 = *(const f32x4*)ga, a1 = *(const f32x4*)(ga+4);
      f32x4 b0 = *(const f32x4*)gb, b1 = *(const f32x4*)(gb+4);
      bf16x8 vah, val, vbh, vbl;
      #pragma unroll
      for (int j=0;j<4;++j){
        unsigned short h;
        h = f2b(a0[j]); vah[j]   = (short)h; val[j]   = (short)f2b(a0[j]-b2f(h));
        h = f2b(a1[j]); vah[4+j] = (short)h; val[4+j] = (short)f2b(a1[j]-b2f(h));
        h = f2b(b0[j]); vbh[j]   = (short)h; vbl[j]   = (short)f2b(b0[j]-b2f(h));
        h = f2b(b1[j]); vbh[4+j] = (short)h; vbl[4+j] = (short)f2b(b1[j]-b2f(h));
      }
      int lb = row*128 + ((k8*16) ^ ((row&7)<<4));
      *(bf16x8*)(AhB + lb) = vah;
      *(bf16x8*)(AlB + lb) = val;
      *(bf16x8*)(BhB + lb) = vbh;
      *(bf16x8*)(BlB + lb) = vbl;
    }
    __syncthreads();
    #pragma unroll
    for (int kk=0; kk<2; ++kk) {
      bf16x8 afh[4], afl[4], bfh[4], bfl[4];
      #pragma unroll
      for (int i=0;i<4;++i){
        int row = wm+i*16+fr;
        int off = row*128 + ((kk*64 + fq*16) ^ ((row&7)<<4));
        afh[i] = *(const bf16x8*)(AhB + off);
        afl[i] = *(const bf16x8*)(AlB + off);
      }
      #pragma unroll
      for (int j=0;j<4;++j){
        int row = wn+j*16+fr;
        int off = row*128 + ((kk*64 + fq*16) ^ ((row&7)<<4));
        bfh[j] = *(const bf16x8*)(BhB + off);
        bfl[j] = *(const bf16x8*)(BlB + off);
      }
      #pragma unroll
      for (int i=0;i<4;++i)
        #pragma unroll
        for (int j=0;j<4;++j){
          acc[i][j] = __builtin_amdgcn_mfma_f32_16x16x32_bf16(afh[i], bfh[j], acc[i][j], 0,0,0);
          acc[i][j] = __builtin_amdgcn_mfma_f32_16x16x32_bf16(afh[i], bfl[j], acc[i][j], 0,0,0);
          acc[i][j] = __builtin_amdgcn_mfma_f32_16x16x32_bf16(afl[i], bfh[j], acc[i][j], 0,0,0);
        }
    }
    __syncthreads();
  }
  #pragma unroll
  for (int j=0;j<4;++j) {
    int col = n0 + wn + j*16 + fr;
    float bv = bias[col];
    #pragma unroll
    for (int i=0;i<4;++i) {
      int rowb = m0 + wm + i*16 + fq*4;
      #pragma unroll
      for (int r=0;r<4;++r) {
        float v = acc[i][j][r] + bv;
        if (MODE==1) v = 1.f/(1.f + expf(-v));
        OUT[(size_t)(rowb+r)*D_DIM + col] = v;
      }
    }
  }
}

// ---- persistent recurrence ----------------------------------------------------
__global__ __launch_bounds__(256, 1)
void rnn_persist(const float* __restrict__ Wh,
                 float* PO,                 // out_o: G (read) / out (write)
                 float* PH,                 // out_h: P (read@t+1 slot) / h (write)
                 float* __restrict__ h_ex)  // [8 grp][16 slot][4096 f32]
{
  __shared__ char  hsb[4*4096];          // h staged, XOR-swizzled 16B granules (16KB)
  __shared__ float part[16*137];         // k-partials, padded stride (8.8KB)

  const int tid = threadIdx.x;
  const int blk = blockIdx.x;
  const int g   = blk & 7;               // chain-group 0..7 (XCD-interleaved)
  const int sl  = blk >> 3;              // e-slice 0..31
  const int e0  = sl * 32;
  const int b0  = g * 4;
  const int e2  = tid & 15;              // e-pair 0..15
  const int kc  = tid >> 4;              // k-chunk 0..15 (64 k each)

  // ---- one-time: Wh slice into registers (2 e-cols x 64 k per thread) ----
  f32x4 wh0[16], wh1[16];
  {
    const f32x4* wp0 = (const f32x4*)(Wh + (size_t)(e0 + 2*e2 + 0)*D_DIM + kc*64);
    const f32x4* wp1 = (const f32x4*)(Wh + (size_t)(e0 + 2*e2 + 1)*D_DIM + kc*64);
    #pragma unroll
    for (int i = 0; i < 16; ++i) { wh0[i] = wp0[i]; wh1[i] = wp1[i]; }
  }

  const int bl = tid >> 5;               // epilogue roles (tid<128): b 0..3
  const int el = tid & 31;               // e 0..31
  float hold = 0.f;                      // this thread's own h[b0+bl][e0+el]

  // prefetch P/G for t=0
  float Pv = 0.f, Gv = 0.f;
  if (tid < 128) {
    size_t idx0 = (size_t)(b0 + bl)*D_DIM + e0 + el;
    Pv = PH[idx0 + 32768];
    Gv = PO[idx0];
  }

  for (int t = 0; t < T_DIM; ++t) {
    size_t idx_out = (size_t)t*32768 + (size_t)(b0 + bl)*D_DIM + e0 + el;

    // stage h[4][1024] from h_ex[g][t&15] — NaN-marker-gated retry (sc1)
    // R13-proven shape: unconditional reloads, waitcnt, sched_barrier(0) (rule #18)
    {
      const char* hsrc = (const char*)(h_ex + ((size_t)g*16 + (t & 15))*4096) + tid*16;
      i32x4 r0, r1, r2, r3;
      while (true) {
        asm volatile("global_load_dwordx4 %0, %1, off sc1" : "=v"(r0) : "v"(hsrc)         : "memory");
        asm volatile("global_load_dwordx4 %0, %1, off sc1" : "=v"(r1) : "v"(hsrc + 4096)  : "memory");
        asm volatile("global_load_dwordx4 %0, %1, off sc1" : "=v"(r2) : "v"(hsrc + 8192)  : "memory");
        asm volatile("global_load_dwordx4 %0, %1, off sc1" : "=v"(r3) : "v"(hsrc + 12288) : "memory");
        asm volatile("s_waitcnt vmcnt(0)" ::: "memory");
        __builtin_amdgcn_sched_barrier(0);
        bool ok = (r0[0]!=(int)NANB) & (r0[1]!=(int)NANB) & (r0[2]!=(int)NANB) & (r0[3]!=(int)NANB)
                & (r1[0]!=(int)NANB) & (r1[1]!=(int)NANB) & (r1[2]!=(int)NANB) & (r1[3]!=(int)NANB)
                & (r2[0]!=(int)NANB) & (r2[1]!=(int)NANB) & (r2[2]!=(int)NANB) & (r2[3]!=(int)NANB)
                & (r3[0]!=(int)NANB) & (r3[1]!=(int)NANB) & (r3[2]!=(int)NANB) & (r3[3]!=(int)NANB);
        if (ok) break;
        __builtin_amdgcn_s_sleep(2);
      }
      // scatter to LDS with XOR swizzle: granule g16 -> g16 ^ (g16>>4), per b-plane
      #pragma unroll
      for (int i = 0; i < 4; ++i) {
        int g16s = tid ^ (tid >> 4);
        i32x4 v = (i==0) ? r0 : (i==1) ? r1 : (i==2) ? r2 : r3;
        *(i32x4*)(hsb + i*4096 + g16s*16) = v;
      }
    }
    __syncthreads();

    // prefetch P/G for t+1 — lands during compute, off the sync chain
    float Pn = 0.f, Gn = 0.f;
    if (t + 1 < T_DIM && tid < 128) {
      size_t idx_n = (size_t)(t+1)*32768 + (size_t)(b0 + bl)*D_DIM + e0 + el;
      Pn = PH[idx_n + 32768];
      Gn = PO[idx_n];
    }

    // compute: acc[b][u] = sum over this thread's 64-k chunk (conflict-free reads)
    float acc[4][2];
    #pragma unroll
    for (int b = 0; b < 4; ++b) { acc[b][0] = 0.f; acc[b][1] = 0.f; }
    #pragma unroll
    for (int i = 0; i < 16; ++i) {
      f32x4 w0 = wh0[i], w1 = wh1[i];
      #pragma unroll
      for (int b = 0; b < 4; ++b) {
        f32x4 hv = *(const f32x4*)(hsb + b*4096 + kc*256 + ((i ^ kc) << 4));
        float d0 = hv[0]*w0[0] + hv[1]*w0[1] + hv[2]*w0[2] + hv[3]*w0[3];
        float d1 = hv[0]*w1[0] + hv[1]*w1[1] + hv[2]*w1[2] + hv[3]*w1[3];
        acc[b][0] += d0;
        acc[b][1] += d1;
      }
    }
    #pragma unroll
    for (int b = 0; b < 4; ++b) {
      part[kc*137 + b*32 + 2*e2 + 0] = acc[b][0];
      part[kc*137 + b*32 + 2*e2 + 1] = acc[b][1];
    }
    __syncthreads();

    // reduce + epilogue (tid<128: one (b,e) each)
    if (tid < 128) {
      float pre = 0.f;
      #pragma unroll
      for (int q = 0; q < 16; ++q) pre += part[q*137 + bl*32 + el];
      pre += Pv;
      float th = tanhf(pre);
      float hn = hold + Gv*th;
      hold = hn;
      float sg = 1.f/(1.f + expf(-hn));
      // 1) exchange store: h -> h_ex[g][(t+1)&15] (sc1; data IS the flag)
      float* hdst = h_ex + ((size_t)g*16 + ((t+1) & 15))*4096 + (size_t)bl*1024 + e0 + el;
      asm volatile("global_store_dword %0, %1, off sc1" :: "v"(hdst), "v"(hn) : "memory");
      // 2) pre-clear my float in slot (t+9)&15 (consumed >=8 steps ago)
      uint32_t nanb = NANB;
      float* ndst = h_ex + ((size_t)g*16 + ((t+9) & 15))*4096 + (size_t)bl*1024 + e0 + el;
      asm volatile("global_store_dword %0, %1, off sc1" :: "v"(ndst), "v"(nanb) : "memory");
      // 3) outputs (plain stores, off the chain)
      PH[idx_out + 32768] = hn;            // h[t+1] (overwrites P slot)
      PO[idx_out] = hn*hn*sg;              // out[t]
    }
    Pv = Pn; Gv = Gn;
    // no trailing barrier/vmcnt/flag — consumers gate on the data itself
  }
}

extern "C" void kernel_launch(void* const* d_in, const int* in_sizes, int n_in,
                              void* d_out, int out_size, void* d_ws, size_t ws_size,
                              hipStream_t stream) {
  const float* x  = (const float*)d_in[0];
  const float* Wh = (const float*)d_in[1];
  const float* Wx = (const float*)d_in[2];
  const float* Wg = (const float*)d_in[3];
  const float* b  = (const float*)d_in[4];
  const float* bg = (const float*)d_in[5];

  float* out_o = (float*)d_out;                       // [T,B,D] fp32
  float* out_h = out_o + (size_t)M_DIM*D_DIM;         // [T+1,B,D] fp32

  float* h_ex = (float*)d_ws;                         // 8*16*16KB = 2 MB

  init_kernel<<<2048, 256, 0, stream>>>(out_h, (uint32_t*)h_ex);
  proj_m<1><<<dim3(8,128), 256, 0, stream>>>(x, Wg, bg, out_o);           // G -> out_o[t]
  proj_m<0><<<dim3(8,128), 256, 0, stream>>>(x, Wx, b,  out_h + 32768);   // P -> out_h[t+1]
  rnn_persist<<<256, 256, 0, stream>>>(Wh, out_o, out_h, h_ex);
}